// Round 4
// baseline (148.259 us; speedup 1.0000x reference)
//
#include <hip/hip_runtime.h>

#define BATCH 4
#define HH 56
#define WW 56
#define CC 128
#define NHD 4
#define HD 32
#define KS 7
#define NB 3
#define HWSZ (HH * WW)        // 3136
#define RPBW 13
#define QKV_N 384
#define QKV_ELE ((size_t)BATCH * NHD * HWSZ * HD)   // 1,605,632 floats per tensor

// ---------------- Kernel 1: QKV GEMM (LDS-free, scalar-A) ----------------
// x [12544,128] @ w_qkv[128,384] + b -> q/k/v each [B,NH,HW,HD], q pre-scaled.
// col-per-thread (384 thr), 16 rows per block (784 blocks = 18 waves/CU).
// x row addresses are wave-uniform -> scalar loads (s_load), no LDS, no barriers.
// w reads are 384-lane coalesced, L2-resident (196 KB).
__global__ __launch_bounds__(384) void qkv_gemm(
    const float* __restrict__ x, const float* __restrict__ w,
    const float* __restrict__ bias,
    float* __restrict__ qb, float* __restrict__ kb, float* __restrict__ vb)
{
    const int col = threadIdx.x;          // 0..383
    const int m0  = blockIdx.x * 16;

    float acc[16];
    const float bv = bias[col];
    #pragma unroll
    for (int r = 0; r < 16; ++r) acc[r] = bv;

    const float* xrow = x + (size_t)m0 * CC;   // uniform base
    const float* wc   = w + col;

    for (int k4 = 0; k4 < 32; ++k4) {
        const float w0 = wc[(k4 * 4 + 0) * QKV_N];
        const float w1 = wc[(k4 * 4 + 1) * QKV_N];
        const float w2 = wc[(k4 * 4 + 2) * QKV_N];
        const float w3 = wc[(k4 * 4 + 3) * QKV_N];
        #pragma unroll
        for (int r = 0; r < 16; ++r) {
            const float4 xv = *(const float4*)(xrow + (size_t)r * CC + k4 * 4); // uniform -> s_load
            acc[r] = fmaf(xv.x, w0, acc[r]);
            acc[r] = fmaf(xv.y, w1, acc[r]);
            acc[r] = fmaf(xv.z, w2, acc[r]);
            acc[r] = fmaf(xv.w, w3, acc[r]);
        }
    }

    // scatter into q/k/v [B,NH,HW,HD]
    const int t    = col >> 7;        // 0=q 1=k 2=v
    const int rem  = col & 127;
    const int head = rem >> 5;
    const int d    = rem & 31;
    const float scl = (t == 0) ? 0.17677669529663687f : 1.0f;  // 32^-0.5
    float* dst = (t == 0) ? qb : (t == 1) ? kb : vb;

    const int b   = m0 / HWSZ;        // 16 | 3136 so tile never crosses b
    const int ij0 = m0 - b * HWSZ;
    float* dsth = dst + (size_t)(b * NHD + head) * HWSZ * HD + d;
    #pragma unroll
    for (int r = 0; r < 16; ++r) {
        dsth[(size_t)(ij0 + r) * HD] = acc[r] * scl;
    }
}

// ---------------- Kernel 2: neighborhood attention ----------------
// Block = 256 threads = 4 waves per (b, head, 8x8 query tile).
// Each query handled by a quad: lane sub=tid&3 owns 8 channels; quad-reduce
// via xor-shuffles. K+V halo staged in LDS (pos padded to 197).
__global__ __launch_bounds__(256) void natten_attn(
    const float* __restrict__ qb, const float* __restrict__ kb,
    const float* __restrict__ vb, const float* __restrict__ rpb,
    float* __restrict__ ob)
{
    __shared__ float4 Ks[8][197];   // [c][pos]
    __shared__ float4 Vs[8][197];
    __shared__ float rpbs[RPBW * RPBW];

    const int tid = threadIdx.x;
    const int qid = tid >> 2;       // 0..63 query within 8x8 tile
    const int sub = tid & 3;        // channel-quarter
    const int qi_l = qid >> 3;
    const int qj_l = qid & 7;
    const int ti = blockIdx.x / 7;
    const int tj = blockIdx.x % 7;
    const int head = blockIdx.y;
    const int b    = blockIdx.z;
    const int qi = ti * 8 + qi_l;
    const int qj = tj * 8 + qj_l;
    const int R0 = min(max(ti * 8 - NB, 0), HH - 14);
    const int C0 = min(max(tj * 8 - NB, 0), WW - 14);

    const size_t base = (size_t)(b * NHD + head) * HWSZ;

    if (tid < RPBW * RPBW) rpbs[tid] = rpb[head * (RPBW * RPBW) + tid];

    // stage K+V halo (8 lanes cover one pixel's 128 B -> coalesced)
    for (int idx = tid; idx < 1568; idx += 256) {
        const int pos = idx >> 3;
        const int c   = idx & 7;
        const int ri  = pos / 14;
        const int rj  = pos - ri * 14;
        const size_t g = (base + (size_t)(R0 + ri) * WW + (C0 + rj)) * HD;
        Ks[c][pos] = ((const float4*)(kb + g))[c];
        Vs[c][pos] = ((const float4*)(vb + g))[c];
    }

    // q fragment: my 8 channels (pre-scaled in qkv_gemm)
    const int c0 = sub * 2;
    const float4* qp = (const float4*)(qb + (base + (size_t)qi * WW + qj) * HD) + c0;
    const float4 q0 = qp[0];
    const float4 q1 = qp[1];

    const int si  = min(max(qi - NB, 0), HH - KS);
    const int sj  = min(max(qj - NB, 0), WW - KS);
    const int ri0 = si - R0;
    const int rj0 = sj - C0;
    const int oi  = si - qi + (KS - 1);
    const int oj  = sj - qj + (KS - 1);

    __syncthreads();

    // scores: partial dot over my 8 channels, quad-reduce via shuffles
    float s[49];
    #pragma unroll
    for (int pi = 0; pi < 7; ++pi) {
        const int rowoff = (ri0 + pi) * 14 + rj0;
        const int boff   = (oi + pi) * RPBW + oj;
        #pragma unroll
        for (int pj = 0; pj < 7; ++pj) {
            const int pos = rowoff + pj;
            const float4 k0 = Ks[c0][pos];
            const float4 k1 = Ks[c0 + 1][pos];
            float d = q0.x * k0.x + q0.y * k0.y + q0.z * k0.z + q0.w * k0.w
                    + q1.x * k1.x + q1.y * k1.y + q1.z * k1.z + q1.w * k1.w;
            d += __shfl_xor(d, 1, 64);
            d += __shfl_xor(d, 2, 64);
            s[pi * 7 + pj] = d + rpbs[boff + pj];
        }
    }

    // softmax (replicated across the quad)
    float m = s[0];
    #pragma unroll
    for (int p = 1; p < 49; ++p) m = fmaxf(m, s[p]);
    float l = 0.f;
    #pragma unroll
    for (int p = 0; p < 49; ++p) { s[p] = __expf(s[p] - m); l += s[p]; }
    const float inv = 1.f / l;

    // PV over my 8 channels
    float4 o0 = make_float4(0.f, 0.f, 0.f, 0.f);
    float4 o1 = make_float4(0.f, 0.f, 0.f, 0.f);
    #pragma unroll
    for (int pi = 0; pi < 7; ++pi) {
        const int rowoff = (ri0 + pi) * 14 + rj0;
        #pragma unroll
        for (int pj = 0; pj < 7; ++pj) {
            const int pos = rowoff + pj;
            const float wt = s[pi * 7 + pj];
            const float4 v0 = Vs[c0][pos];
            const float4 v1 = Vs[c0 + 1][pos];
            o0.x += wt * v0.x; o0.y += wt * v0.y; o0.z += wt * v0.z; o0.w += wt * v0.w;
            o1.x += wt * v1.x; o1.y += wt * v1.y; o1.z += wt * v1.z; o1.w += wt * v1.w;
        }
    }

    // write [B,H,W,NH*HD]; quad writes one pixel's 32-ch slice
    float* op = ob + ((size_t)b * HWSZ + (size_t)qi * WW + qj) * CC + head * HD + sub * 8;
    ((float4*)op)[0] = make_float4(o0.x * inv, o0.y * inv, o0.z * inv, o0.w * inv);
    ((float4*)op)[1] = make_float4(o1.x * inv, o1.y * inv, o1.z * inv, o1.w * inv);
}

// ---------------- Kernel 3: output projection (LDS-free, scalar-A) ----------------
// a [12544,128] @ w_proj[128,128] + b_proj. col-per-thread (128 thr),
// 16 rows per block (784 blocks). Same scalar-A / coalesced-B structure.
__global__ __launch_bounds__(128) void proj_gemm(
    const float* __restrict__ a, const float* __restrict__ w,
    const float* __restrict__ bias, float* __restrict__ out)
{
    const int col = threadIdx.x;          // 0..127
    const int m0  = blockIdx.x * 16;

    float acc[16];
    const float bv = bias[col];
    #pragma unroll
    for (int r = 0; r < 16; ++r) acc[r] = bv;

    const float* arow = a + (size_t)m0 * CC;   // uniform base
    const float* wc   = w + col;

    for (int k4 = 0; k4 < 32; ++k4) {
        const float w0 = wc[(k4 * 4 + 0) * CC];
        const float w1 = wc[(k4 * 4 + 1) * CC];
        const float w2 = wc[(k4 * 4 + 2) * CC];
        const float w3 = wc[(k4 * 4 + 3) * CC];
        #pragma unroll
        for (int r = 0; r < 16; ++r) {
            const float4 av = *(const float4*)(arow + (size_t)r * CC + k4 * 4); // uniform -> s_load
            acc[r] = fmaf(av.x, w0, acc[r]);
            acc[r] = fmaf(av.y, w1, acc[r]);
            acc[r] = fmaf(av.z, w2, acc[r]);
            acc[r] = fmaf(av.w, w3, acc[r]);
        }
    }

    float* op = out + (size_t)m0 * CC + col;
    #pragma unroll
    for (int r = 0; r < 16; ++r) op[(size_t)r * CC] = acc[r];
}

extern "C" void kernel_launch(void* const* d_in, const int* in_sizes, int n_in,
                              void* d_out, int out_size, void* d_ws, size_t ws_size,
                              hipStream_t stream) {
    const float* x      = (const float*)d_in[0];
    const float* w_qkv  = (const float*)d_in[1];
    const float* b_qkv  = (const float*)d_in[2];
    const float* rpb    = (const float*)d_in[3];
    const float* w_proj = (const float*)d_in[4];
    const float* b_proj = (const float*)d_in[5];
    float* out = (float*)d_out;

    float* ws  = (float*)d_ws;
    float* qbf = ws;
    float* kbf = ws + QKV_ELE;
    float* vbf = ws + 2 * QKV_ELE;
    float* obf = ws + 3 * QKV_ELE;

    qkv_gemm<<<784, 384, 0, stream>>>(x, w_qkv, b_qkv, qbf, kbf, vbf);
    natten_attn<<<dim3(49, NHD, BATCH), 256, 0, stream>>>(qbf, kbf, vbf, rpb, obf);
    proj_gemm<<<784, 128, 0, stream>>>(obf, w_proj, b_proj, out);
}

// Round 5
// 141.103 us; speedup vs baseline: 1.0507x; 1.0507x over previous
//
#include <hip/hip_runtime.h>

#define BATCH 4
#define HH 56
#define WW 56
#define CC 128
#define NHD 4
#define HD 32
#define KS 7
#define NB 3
#define HWSZ (HH * WW)        // 3136
#define RPBW 13
#define QKV_N 384
#define QKV_ELE ((size_t)BATCH * NHD * HWSZ * HD)   // 1,605,632 floats per tensor

// ---------------- Kernel 1: QKV GEMM ----------------
// x [12544,128] @ w_qkv[128,384] + b -> q/k/v each [B,NH,HW,HD], q pre-scaled.
// 64x128 tile, 256 thr, 4x8 micro. A staged transposed in LDS for FULL K=128
// (one barrier), read as a single ds_read_b128/kk. B streamed from L2 with
// coalesced float4 loads (w is L2-resident; wave dedups 4x). No hot-loop
// barriers; compiler pipelines B loads with vmcnt.
__global__ __launch_bounds__(256) void qkv_gemm(
    const float* __restrict__ x, const float* __restrict__ w,
    const float* __restrict__ bias,
    float* __restrict__ qb, float* __restrict__ kb, float* __restrict__ vb)
{
    __shared__ float As[128][68];   // [k][m], 64 rows + pad (16B-aligned rows)

    const int tid = threadIdx.x;
    const int tx  = tid & 15;       // col group: cols 4tx, 64+4tx
    const int ty  = tid >> 4;       // row group: rows 4ty..4ty+3
    const int m0  = blockIdx.x * 64;
    const int n0  = blockIdx.y * 128;

    // stage x^T: 64 rows x 32 k-quads = 2048 float4 tasks, coalesced reads.
    // (LDS writes are bank-conflicted but one-time, ~3% of block cycles.)
    #pragma unroll
    for (int t = tid; t < 2048; t += 256) {
        const int row = t >> 5;
        const int k4  = t & 31;
        const float4 xv = *(const float4*)(x + (size_t)(m0 + row) * CC + 4 * k4);
        As[4 * k4 + 0][row] = xv.x;
        As[4 * k4 + 1][row] = xv.y;
        As[4 * k4 + 2][row] = xv.z;
        As[4 * k4 + 3][row] = xv.w;
    }

    float acc[4][8];
    {
        const float4 ba = *(const float4*)(bias + n0 + 4 * tx);
        const float4 bb = *(const float4*)(bias + n0 + 64 + 4 * tx);
        #pragma unroll
        for (int i = 0; i < 4; ++i) {
            acc[i][0] = ba.x; acc[i][1] = ba.y; acc[i][2] = ba.z; acc[i][3] = ba.w;
            acc[i][4] = bb.x; acc[i][5] = bb.y; acc[i][6] = bb.z; acc[i][7] = bb.w;
        }
    }

    __syncthreads();   // the only barrier

    const float* wp0 = w + n0 + 4 * tx;
    const float* wp1 = w + n0 + 64 + 4 * tx;
    #pragma unroll 4
    for (int kk = 0; kk < 128; ++kk) {
        const float4 b0 = *(const float4*)(wp0 + (size_t)kk * QKV_N);
        const float4 b1 = *(const float4*)(wp1 + (size_t)kk * QKV_N);
        const float4 a0 = *(const float4*)&As[kk][4 * ty];
        const float av[4] = {a0.x, a0.y, a0.z, a0.w};
        const float bv[8] = {b0.x, b0.y, b0.z, b0.w, b1.x, b1.y, b1.z, b1.w};
        #pragma unroll
        for (int i = 0; i < 4; ++i)
            #pragma unroll
            for (int j = 0; j < 8; ++j)
                acc[i][j] = fmaf(av[i], bv[j], acc[i][j]);
    }

    // scatter into q/k/v [B,NH,HW,HD]; n-tile == tensor boundary so t uniform
    const int t     = n0 >> 7;   // 0=q 1=k 2=v
    float* dst      = (t == 0) ? qb : (t == 1) ? kb : vb;
    const float scl = (t == 0) ? 0.17677669529663687f : 1.0f;  // 32^-0.5
    const int c0 = 4 * tx;
    const int c1 = 64 + 4 * tx;
    const int h0 = c0 >> 5, d0 = c0 & 31;
    const int h1 = c1 >> 5, d1 = c1 & 31;
    const int b  = m0 / HWSZ;        // 64 | 3136 so tile never crosses b
    #pragma unroll
    for (int i = 0; i < 4; ++i) {
        const int m  = m0 + 4 * ty + i;
        const int ij = m - b * HWSZ;
        float* p0 = dst + ((size_t)(b * NHD + h0) * HWSZ + ij) * HD + d0;
        float* p1 = dst + ((size_t)(b * NHD + h1) * HWSZ + ij) * HD + d1;
        *(float4*)p0 = make_float4(acc[i][0] * scl, acc[i][1] * scl,
                                   acc[i][2] * scl, acc[i][3] * scl);
        *(float4*)p1 = make_float4(acc[i][4] * scl, acc[i][5] * scl,
                                   acc[i][6] * scl, acc[i][7] * scl);
    }
}

// ---------------- Kernel 2: neighborhood attention (R3-verified) ----------------
// Block = 256 threads = 4 waves per (b, head, 8x8 query tile).
// Each query handled by a quad: lane sub=tid&3 owns 8 channels; quad-reduce
// via xor-shuffles. K+V halo staged in LDS (pos padded to 197).
__global__ __launch_bounds__(256) void natten_attn(
    const float* __restrict__ qb, const float* __restrict__ kb,
    const float* __restrict__ vb, const float* __restrict__ rpb,
    float* __restrict__ ob)
{
    __shared__ float4 Ks[8][197];   // [c][pos]
    __shared__ float4 Vs[8][197];
    __shared__ float rpbs[RPBW * RPBW];

    const int tid = threadIdx.x;
    const int qid = tid >> 2;       // 0..63 query within 8x8 tile
    const int sub = tid & 3;        // channel-quarter
    const int qi_l = qid >> 3;
    const int qj_l = qid & 7;
    const int ti = blockIdx.x / 7;
    const int tj = blockIdx.x % 7;
    const int head = blockIdx.y;
    const int b    = blockIdx.z;
    const int qi = ti * 8 + qi_l;
    const int qj = tj * 8 + qj_l;
    const int R0 = min(max(ti * 8 - NB, 0), HH - 14);
    const int C0 = min(max(tj * 8 - NB, 0), WW - 14);

    const size_t base = (size_t)(b * NHD + head) * HWSZ;

    if (tid < RPBW * RPBW) rpbs[tid] = rpb[head * (RPBW * RPBW) + tid];

    // stage K+V halo (8 lanes cover one pixel's 128 B -> coalesced)
    for (int idx = tid; idx < 1568; idx += 256) {
        const int pos = idx >> 3;
        const int c   = idx & 7;
        const int ri  = pos / 14;
        const int rj  = pos - ri * 14;
        const size_t g = (base + (size_t)(R0 + ri) * WW + (C0 + rj)) * HD;
        Ks[c][pos] = ((const float4*)(kb + g))[c];
        Vs[c][pos] = ((const float4*)(vb + g))[c];
    }

    // q fragment: my 8 channels (pre-scaled in qkv_gemm)
    const int c0 = sub * 2;
    const float4* qp = (const float4*)(qb + (base + (size_t)qi * WW + qj) * HD) + c0;
    const float4 q0 = qp[0];
    const float4 q1 = qp[1];

    const int si  = min(max(qi - NB, 0), HH - KS);
    const int sj  = min(max(qj - NB, 0), WW - KS);
    const int ri0 = si - R0;
    const int rj0 = sj - C0;
    const int oi  = si - qi + (KS - 1);
    const int oj  = sj - qj + (KS - 1);

    __syncthreads();

    // scores: partial dot over my 8 channels, quad-reduce via shuffles
    float s[49];
    #pragma unroll
    for (int pi = 0; pi < 7; ++pi) {
        const int rowoff = (ri0 + pi) * 14 + rj0;
        const int boff   = (oi + pi) * RPBW + oj;
        #pragma unroll
        for (int pj = 0; pj < 7; ++pj) {
            const int pos = rowoff + pj;
            const float4 k0 = Ks[c0][pos];
            const float4 k1 = Ks[c0 + 1][pos];
            float d = q0.x * k0.x + q0.y * k0.y + q0.z * k0.z + q0.w * k0.w
                    + q1.x * k1.x + q1.y * k1.y + q1.z * k1.z + q1.w * k1.w;
            d += __shfl_xor(d, 1, 64);
            d += __shfl_xor(d, 2, 64);
            s[pi * 7 + pj] = d + rpbs[boff + pj];
        }
    }

    // softmax (replicated across the quad)
    float m = s[0];
    #pragma unroll
    for (int p = 1; p < 49; ++p) m = fmaxf(m, s[p]);
    float l = 0.f;
    #pragma unroll
    for (int p = 0; p < 49; ++p) { s[p] = __expf(s[p] - m); l += s[p]; }
    const float inv = 1.f / l;

    // PV over my 8 channels
    float4 o0 = make_float4(0.f, 0.f, 0.f, 0.f);
    float4 o1 = make_float4(0.f, 0.f, 0.f, 0.f);
    #pragma unroll
    for (int pi = 0; pi < 7; ++pi) {
        const int rowoff = (ri0 + pi) * 14 + rj0;
        #pragma unroll
        for (int pj = 0; pj < 7; ++pj) {
            const int pos = rowoff + pj;
            const float wt = s[pi * 7 + pj];
            const float4 v0 = Vs[c0][pos];
            const float4 v1 = Vs[c0 + 1][pos];
            o0.x += wt * v0.x; o0.y += wt * v0.y; o0.z += wt * v0.z; o0.w += wt * v0.w;
            o1.x += wt * v1.x; o1.y += wt * v1.y; o1.z += wt * v1.z; o1.w += wt * v1.w;
        }
    }

    // write [B,H,W,NH*HD]; quad writes one pixel's 32-ch slice
    float* op = ob + ((size_t)b * HWSZ + (size_t)qi * WW + qj) * CC + head * HD + sub * 8;
    ((float4*)op)[0] = make_float4(o0.x * inv, o0.y * inv, o0.z * inv, o0.w * inv);
    ((float4*)op)[1] = make_float4(o1.x * inv, o1.y * inv, o1.z * inv, o1.w * inv);
}

// ---------------- Kernel 3: output projection ----------------
// a [12544,128] @ w_proj[128,128] + b_proj. 32x128 tile, 256 thr, 2x8 micro.
// Same structure as qkv: A transposed in LDS (full K), B streamed from L2.
__global__ __launch_bounds__(256) void proj_gemm(
    const float* __restrict__ a, const float* __restrict__ w,
    const float* __restrict__ bias, float* __restrict__ out)
{
    __shared__ float As[128][36];   // [k][m], 32 rows + pad

    const int tid = threadIdx.x;
    const int tx  = tid & 15;
    const int ty  = tid >> 4;       // rows 2ty, 2ty+1
    const int m0  = blockIdx.x * 32;

    #pragma unroll
    for (int t = tid; t < 1024; t += 256) {
        const int row = t >> 5;
        const int k4  = t & 31;
        const float4 xv = *(const float4*)(a + (size_t)(m0 + row) * CC + 4 * k4);
        As[4 * k4 + 0][row] = xv.x;
        As[4 * k4 + 1][row] = xv.y;
        As[4 * k4 + 2][row] = xv.z;
        As[4 * k4 + 3][row] = xv.w;
    }

    float acc[2][8];
    {
        const float4 ba = *(const float4*)(bias + 4 * tx);
        const float4 bb = *(const float4*)(bias + 64 + 4 * tx);
        #pragma unroll
        for (int i = 0; i < 2; ++i) {
            acc[i][0] = ba.x; acc[i][1] = ba.y; acc[i][2] = ba.z; acc[i][3] = ba.w;
            acc[i][4] = bb.x; acc[i][5] = bb.y; acc[i][6] = bb.z; acc[i][7] = bb.w;
        }
    }

    __syncthreads();

    const float* wp0 = w + 4 * tx;
    const float* wp1 = w + 64 + 4 * tx;
    #pragma unroll 4
    for (int kk = 0; kk < 128; ++kk) {
        const float4 b0 = *(const float4*)(wp0 + (size_t)kk * CC);
        const float4 b1 = *(const float4*)(wp1 + (size_t)kk * CC);
        const float2 a0 = *(const float2*)&As[kk][2 * ty];
        const float av[2] = {a0.x, a0.y};
        const float bv[8] = {b0.x, b0.y, b0.z, b0.w, b1.x, b1.y, b1.z, b1.w};
        #pragma unroll
        for (int i = 0; i < 2; ++i)
            #pragma unroll
            for (int j = 0; j < 8; ++j)
                acc[i][j] = fmaf(av[i], bv[j], acc[i][j]);
    }

    #pragma unroll
    for (int i = 0; i < 2; ++i) {
        const int m = m0 + 2 * ty + i;
        float* p = out + (size_t)m * CC;
        *(float4*)(p + 4 * tx)      = make_float4(acc[i][0], acc[i][1], acc[i][2], acc[i][3]);
        *(float4*)(p + 64 + 4 * tx) = make_float4(acc[i][4], acc[i][5], acc[i][6], acc[i][7]);
    }
}

extern "C" void kernel_launch(void* const* d_in, const int* in_sizes, int n_in,
                              void* d_out, int out_size, void* d_ws, size_t ws_size,
                              hipStream_t stream) {
    const float* x      = (const float*)d_in[0];
    const float* w_qkv  = (const float*)d_in[1];
    const float* b_qkv  = (const float*)d_in[2];
    const float* rpb    = (const float*)d_in[3];
    const float* w_proj = (const float*)d_in[4];
    const float* b_proj = (const float*)d_in[5];
    float* out = (float*)d_out;

    float* ws  = (float*)d_ws;
    float* qbf = ws;
    float* kbf = ws + QKV_ELE;
    float* vbf = ws + 2 * QKV_ELE;
    float* obf = ws + 3 * QKV_ELE;

    qkv_gemm<<<dim3(196, 3), 256, 0, stream>>>(x, w_qkv, b_qkv, qbf, kbf, vbf);
    natten_attn<<<dim3(49, NHD, BATCH), 256, 0, stream>>>(qbf, kbf, vbf, rpb, obf);
    proj_gemm<<<392, 256, 0, stream>>>(obf, w_proj, b_proj, out);
}